// Round 1
// baseline (11671.015 us; speedup 1.0000x reference)
//
#include <hip/hip_runtime.h>
#include <stdint.h>

#define N 4096
#define D 1024
#define TILE 512           // rows per tile (8 tiles per round)
#define THRF 0.25f
#define GBK 16
#define LSTR 4224          // u16 entries per row list slot (4096 + 128 sentinel pad)

// ---- All scratch lives in d_in[0] (16 MB; harness restores it before every
// timed launch; we copy E to d_out first on-stream). d_ws is never used.
// Numerics invariant (R6..R13-proven): sims = fp32( fp64_fma_chain(d=0..1023)/1024 ),
// ALL comparisons in fp32, (val desc, idx asc) ordering — matches np exactly.
// R15 structure: top-K spec + sequential validator replaced by EXACT per-row
// candidate lists: k_sort bitonic-sorts every candidate with v>=thr (j>i, alive,
// !consumed-at-tile-start) into descending (val, idx-asc) order and stores only
// u16 column ids (position encodes order). k_walk (one wave) pops the first
// still-available entry per row against a 4096-bit register bitset. Exactness:
// the list is a superset of candidates available at the row's turn (consumed
// only grows), so first-available-in-sorted-order == true argmax; an exhausted
// list proves no available candidate >= thr. No rescans exist by construction.
// The walk bitset folds (consumed | dead) together; k_apply/k_zero tolerate the
// merged mask (re-zeroing dead rows is idempotent, alive bits already 0).

__global__ void k_init(uint8_t* alive, uint8_t* mgB, int* mcnt, int* acnt) {
    int x = blockIdx.x * blockDim.x + threadIdx.x;
    if (x < N) { alive[x] = 1; mgB[x] = 0; }
    if (x < 8) { mcnt[x] = 0; acnt[x] = (x == 0) ? N : 0; }
}

// fp64 LDS-tiled GEMM -> fp32 sim tile. Rows i in [t0,t0+512), cols j in [bx0*64, 4096).
// UNCHANGED from the verified version (numerics-critical).
__global__ __launch_bounds__(256) void k_gemm(const float* __restrict__ E,
                                              float* __restrict__ simT,
                                              int t0, int bx0) {
    int bi = blockIdx.y;            // row block within tile: 0..7
    int bj = blockIdx.x + bx0;      // column block: bx0..63
    __shared__ float As[64][GBK + 1];
    __shared__ float Bs[64][GBK + 1];
    int t = threadIdx.x;
    int tr = t >> 4, tc = t & 15;
    double acc[4][4] = {};
    const float* Arow = E + ((size_t)t0 + (size_t)bi * 64) * D;
    const float* Brow = E + (size_t)bj * 64 * D;
    for (int k0 = 0; k0 < D; k0 += GBK) {
        for (int q = 0; q < 4; ++q) {
            int lin = t + 256 * q;           // 0..1023
            int r = lin >> 4, c = lin & 15;
            As[r][c] = Arow[(size_t)r * D + k0 + c];
            Bs[r][c] = Brow[(size_t)r * D + k0 + c];
        }
        __syncthreads();
        for (int kk = 0; kk < GBK; ++kk) {
            double a[4], b[4];
            for (int u = 0; u < 4; ++u) a[u] = (double)As[tr * 4 + u][kk];
            for (int v = 0; v < 4; ++v) b[v] = (double)Bs[tc * 4 + v][kk];
            for (int u = 0; u < 4; ++u)
                for (int v = 0; v < 4; ++v) acc[u][v] = fma(a[u], b[v], acc[u][v]);
        }
        __syncthreads();
    }
    int rbase = bi * 64 + tr * 4;
    int jbase = bj * 64 + tc * 4;
    for (int u = 0; u < 4; ++u)
        for (int v = 0; v < 4; ++v)
            simT[(size_t)(rbase + u) * N + (jbase + v)] =
                (float)(acc[u][v] * (1.0 / 1024.0));
}

// Exact per-row candidate list: bitonic sort of 64-bit keys ((~v_bits)<<32)|j
// ascending == (v desc, j asc). Only entries with v>=thr & j>i & alive[j] &
// !mg[j]-at-tile-start participate; everything else sorts to the end as ~0.
// Output: u16 column ids, 0xFFFF sentinel, [sortN, sortN+128) sentinel pad so
// the walk's 126-entry chunks can never over-read into the next row.
// sortN/cb shrink the sort for late tiles (all valid j >= cb).
__global__ __launch_bounds__(256) void k_sort(const float* __restrict__ simT,
                                              const uint8_t* __restrict__ alive,
                                              const uint8_t* __restrict__ mgG,
                                              int t0, int sortN, int cb,
                                              uint16_t* __restrict__ lists) {
    int r = blockIdx.x;
    int i = t0 + r;
    int t = threadIdx.x;
    __shared__ uint64_t key[4096];           // 32 KB
    uint16_t* out = lists + (size_t)r * LSTR;
    if (!alive[i] || mgG[i]) {               // row dead/consumed: walk skips it
        if (t < 128) out[t] = (uint16_t)0xFFFFu;   // safety sentinels
        return;
    }
    const float* row = simT + (size_t)r * N;
    for (int jj = t; jj < sortN; jj += 256) {
        int j = cb + jj;
        float v = row[j];
        // NaN-safe: NaN fails v>=THRF; stale simT regions are masked by j>i.
        bool ok = (j > i) && (v >= THRF) && alive[j] && (!mgG[j]);
        uint32_t vb = __float_as_uint(v);    // v>0 => bit pattern monotone
        key[jj] = ok ? ((((uint64_t)(~vb)) << 32) | (uint32_t)j) : ~0ull;
    }
    __syncthreads();
    for (int k = 2; k <= sortN; k <<= 1) {
        for (int s = k >> 1; s > 0; s >>= 1) {
            for (int jj = t; jj < sortN; jj += 256) {
                int l = jj ^ s;
                if (l > jj) {
                    uint64_t a = key[jj], b = key[l];
                    bool asc = ((jj & k) == 0);
                    if ((a > b) == asc) { key[jj] = b; key[l] = a; }
                }
            }
            __syncthreads();
        }
    }
    for (int jj = t; jj < sortN; jj += 256) {
        uint64_t kk = key[jj];
        out[jj] = (kk == ~0ull) ? (uint16_t)0xFFFFu : (uint16_t)(kk & 0xFFFFu);
    }
    for (int j2 = t; j2 < 128; j2 += 256) out[sortN + j2] = (uint16_t)0xFFFFu;
}

// Single-wave exact walk. Lane 0 carries the row's own (consumed|dead) check;
// lanes 1..63 carry 2 list entries each (126/chunk). One shfl+ballot resolves
// skip/pick/refill. mw bit x = mgG[x] | !alive[x]; writeback of the merged
// mask is safe for all downstream consumers (see header comment).
__global__ __launch_bounds__(64) void k_walk(const uint16_t* __restrict__ lists,
                                             const uint8_t* __restrict__ aliveG,
                                             uint8_t* __restrict__ mgG,
                                             int* __restrict__ partner,
                                             int t0, int* __restrict__ mcnt, int round) {
    int lane = threadIdx.x;
    unsigned long long mw = 0ull;            // bit x = unavailable (consumed|dead)
    for (int w = 0; w < 8; ++w) {
        unsigned long long gm = ((const unsigned long long*)mgG)[lane * 8 + w];
        unsigned long long ga = ((const unsigned long long*)aliveG)[lane * 8 + w];
        unsigned long long bad = gm | (ga ^ 0x0101010101010101ull);  // bytes are 0/1
        for (int k = 0; k < 8; ++k)
            mw |= ((bad >> (8 * k)) & 1ull) << (8 * w + k);
    }
    __shared__ int pt[TILE];
    int nm = 0;
    int eoff = (lane ? (lane - 1) : 0) * 2;  // lane0 duplicates lane1's load (unused)
    ushort2 A = *(const ushort2*)(lists + eoff);
    ushort2 Bf = *(const ushort2*)(lists + (size_t)LSTR + eoff);
    for (int r = 0; r < TILE; ++r) {
        ushort2 Cf = Bf;                     // 2-deep prefetch of next rows' chunk0
        if (r + 2 < TILE)
            Cf = *(const ushort2*)(lists + (size_t)(r + 2) * LSTR + eoff);
        int i = t0 + r;
        ushort2 ch = A;
        int base = 0;
        int pj = -1;
        while (true) {
            int c0, c1; bool v0, v1;
            if (lane == 0) { c0 = i; v0 = true; c1 = 0; v1 = false; }
            else {
                v0 = (ch.x != 0xFFFFu); c0 = v0 ? (int)ch.x : 0;
                v1 = (ch.y != 0xFFFFu); c1 = v1 ? (int)ch.y : 0;
            }
            unsigned long long w0 = __shfl(mw, c0 >> 6);
            unsigned long long w1 = __shfl(mw, c1 >> 6);
            bool a0 = v0 && !((w0 >> (c0 & 63)) & 1ull);
            bool a1 = v1 && !((w1 >> (c1 & 63)) & 1ull);
            unsigned long long bal = __ballot(a0 || a1);
            if (!(bal & 1ull)) break;        // row itself consumed/dead -> -1
            unsigned long long m = bal & ~1ull;
            if (m) {
                int f = __ffsll((long long)m) - 1;
                int cpick = a0 ? c0 : c1;    // within-lane order: entry0 first
                pj = __shfl(cpick, f);
                break;
            }
            unsigned long long vb = __ballot(v1);     // chunk full <=> lanes1..63 all v1
            if ((vb | 1ull) != ~0ull) break;          // sentinel seen: no cand >= thr
            base += 126;
            if (base + 126 > LSTR) break;             // safety (pad makes this unreachable)
            ch = *(const ushort2*)(lists + (size_t)r * LSTR + base + eoff);
        }
        if (pj >= 0) {
            if (lane == (pj >> 6)) mw |= 1ull << (pj & 63);
            if (lane == 0) pt[r] = pj;
            ++nm;                            // wave-uniform
        } else if (lane == 0) pt[r] = -1;
        A = Bf; Bf = Cf;
    }
    for (int r2 = lane; r2 < TILE; r2 += 64) partner[t0 + r2] = pt[r2];
    for (int w = 0; w < 8; ++w) {
        unsigned long long x = 0ull;
        for (int k = 0; k < 8; ++k)
            x |= ((mw >> (8 * w + k)) & 1ull) << (8 * k);
        ((unsigned long long*)mgG)[lane * 8 + w] = x;  // merged mask: safe (see header)
    }
    if (lane == 0 && nm) atomicAdd(&mcnt[round], nm);
}

__global__ void k_apply(uint8_t* __restrict__ mgB,
                        uint8_t* __restrict__ alive, uint8_t* __restrict__ consumed) {
    int x = blockIdx.x * blockDim.x + threadIdx.x;
    if (x < N) {
        uint8_t m = mgB[x];
        consumed[x] = m;                     // may include long-dead rows: k_zero idempotent
        alive[x] = (uint8_t)(alive[x] && !m);
        mgB[x] = 0;                          // reset for next round (k_mgzero folded in)
    }
}

__global__ __launch_bounds__(256) void k_count(const uint8_t* __restrict__ alive,
                                               int* __restrict__ acnt, int slot) {
    int x = blockIdx.x * 256 + threadIdx.x;
    int lane = threadIdx.x & 63;
    unsigned long long b = __ballot(alive[x] != 0);
    if (lane == 0) atomicAdd(&acnt[slot], (int)__popcll(b));
}

__global__ void k_fuse(float* __restrict__ E, const int* __restrict__ partner) {
    int i = blockIdx.x;
    int p = partner[i];
    if (p < 0) return;
    float* ri = E + (size_t)i * D;
    const float* rp = E + (size_t)p * D;
    for (int e = threadIdx.x; e < D; e += blockDim.x)
        ri[e] = fminf(ri[e] + rp[e], 1.0f);
}

__global__ void k_zero(float* __restrict__ E, const uint8_t* __restrict__ consumed) {
    int i = blockIdx.x;
    if (!consumed[i]) return;
    float* ri = E + (size_t)i * D;
    for (int e = threadIdx.x; e < D; e += blockDim.x) ri[e] = 0.0f;
}

__global__ void k_alive_out(const uint8_t* __restrict__ alive, float* __restrict__ outA) {
    int x = blockIdx.x * blockDim.x + threadIdx.x;
    if (x < N) outA[x] = alive[x] ? 1.0f : 0.0f;
}

// AUDIT: fires ONLY on invariant violation (after+m==before, 2m<=before).
__global__ void k_diag(const int* __restrict__ mcnt, const int* __restrict__ acnt,
                       float* __restrict__ out) {
    bool bad = false;
    for (int r = 0; r < 4; ++r) {
        int before = acnt[r], after = acnt[r + 1], m = mcnt[r];
        if (after + m != before) bad = true;
        if (2 * m > before) bad = true;
        if (m < 0 || m > 2048) bad = true;
    }
    if (bad) out[0] = (float)(8.0e6 + (double)mcnt[0] * 2048.0 + (double)mcnt[1]);
}

extern "C" void kernel_launch(void* const* d_in, const int* in_sizes, int n_in,
                              void* d_out, int out_size, void* d_ws, size_t ws_size,
                              hipStream_t stream) {
    const float* Ein = (const float*)d_in[0];
    float* E = (float*)d_out;                    // 4096*1024 fp32, updated in place
    float* outAlive = E + (size_t)N * D;         // 4096 floats (0/1)

    // arena = d_in[0] after the on-stream copy below (16 MB guaranteed)
    char* ws = (char*)d_in[0];
    float* simT = (float*)ws;        ws += (size_t)TILE * N * 4;      // 8 MB
    uint16_t* lists = (uint16_t*)ws; ws += (size_t)TILE * LSTR * 2;   // 4.125 MB
    int* partner = (int*)ws;         ws += (size_t)N * 4;             // 16 KB
    int* mcnt = (int*)ws;            ws += 8 * 4;
    int* acnt = (int*)ws;            ws += 8 * 4;
    uint8_t* mgB = (uint8_t*)ws;     ws += N;    // 8B-aligned (all prior sizes %8==0)
    uint8_t* alive = (uint8_t*)ws;   ws += N;
    uint8_t* consumed = (uint8_t*)ws;            // total ~12.4 MB << 16 MB

    hipMemcpyAsync(E, Ein, (size_t)N * D * sizeof(float), hipMemcpyDeviceToDevice, stream);
    k_init<<<(N + 255) / 256, 256, 0, stream>>>(alive, mgB, mcnt, acnt);

    for (int round = 0; round < 4; ++round) {
        for (int tile = 0; tile < N / TILE; ++tile) {
            int t0 = tile * TILE;
            int bx0 = t0 / 64;                    // skip never-read columns j < t0
            int rem = N - t0;
            int sortN = 1; while (sortN < rem) sortN <<= 1;
            int cb = N - sortN;                   // all valid j > i >= t0 >= cb
            k_gemm<<<dim3(64 - bx0, TILE / 64), 256, 0, stream>>>(E, simT, t0, bx0);
            k_sort<<<TILE, 256, 0, stream>>>(simT, alive, mgB, t0, sortN, cb, lists);
            k_walk<<<1, 64, 0, stream>>>(lists, alive, mgB, partner, t0, mcnt, round);
        }
        k_apply<<<(N + 255) / 256, 256, 0, stream>>>(mgB, alive, consumed);
        k_count<<<16, 256, 0, stream>>>(alive, acnt, round + 1);
        k_fuse<<<N, 256, 0, stream>>>(E, partner);
        k_zero<<<N, 256, 0, stream>>>(E, consumed);
    }
    k_alive_out<<<(N + 255) / 256, 256, 0, stream>>>(alive, outAlive);
    k_diag<<<1, 1, 0, stream>>>(mcnt, acnt, E);   // conditional sentinel only
}

// Round 2
// 9081.099 us; speedup vs baseline: 1.2852x; 1.2852x over previous
//
#include <hip/hip_runtime.h>
#include <stdint.h>

#define N 4096
#define D 1024
#define TILE 512           // rows per tile (8 tiles per round)
#define THRF 0.25f
#define GBK 16
#define LSTR 4224          // u16 entries per row list slot (4096 + 128 sentinel pad)

// ---- All scratch lives in d_in[0] (16 MB; harness restores it before every
// timed launch; we copy E to d_out first on-stream). d_ws is never used.
// Numerics invariant (R6..R13-proven): sims = fp32( fp64_fma_chain(d=0..1023)/1024 ),
// ALL comparisons in fp32, (val desc, idx asc) ordering — matches np exactly.
// R16 structure (R15 + perf): exact per-row candidate lists. k_sort now
// ballot-COMPACTS the passing candidates (j>i, alive, !mg-at-tile-start,
// v>=thr) and bitonic-sorts only next_pow2(m) keys with 1024 threads
// (occupancy fix). Compaction is order-agnostic: the 64-bit key
// ((~v_bits)<<32)|j imposes the same total order (val desc, idx asc) on the
// same set, so the emitted list is bit-identical to the full-sort version.
// k_walk preloads every row's chunk0 into LDS with 15 helper waves; wave 0
// walks against a 4096-bit register bitset reading LDS (no global-prefetch
// stall). Exactness argument unchanged: lists are a superset of candidates
// available at the row's turn; first available in sorted order == argmax;
// exhausted list (sentinel before any available) proves no candidate >= thr.

__global__ void k_init(uint8_t* alive, uint8_t* mgB, int* mcnt, int* acnt) {
    int x = blockIdx.x * blockDim.x + threadIdx.x;
    if (x < N) { alive[x] = 1; mgB[x] = 0; }
    if (x < 8) { mcnt[x] = 0; acnt[x] = (x == 0) ? N : 0; }
}

// fp64 LDS-tiled GEMM -> fp32 sim tile. Rows i in [t0,t0+512), cols j in [bx0*64, 4096).
// UNCHANGED from the verified version (numerics-critical).
__global__ __launch_bounds__(256) void k_gemm(const float* __restrict__ E,
                                              float* __restrict__ simT,
                                              int t0, int bx0) {
    int bi = blockIdx.y;            // row block within tile: 0..7
    int bj = blockIdx.x + bx0;      // column block: bx0..63
    __shared__ float As[64][GBK + 1];
    __shared__ float Bs[64][GBK + 1];
    int t = threadIdx.x;
    int tr = t >> 4, tc = t & 15;
    double acc[4][4] = {};
    const float* Arow = E + ((size_t)t0 + (size_t)bi * 64) * D;
    const float* Brow = E + (size_t)bj * 64 * D;
    for (int k0 = 0; k0 < D; k0 += GBK) {
        for (int q = 0; q < 4; ++q) {
            int lin = t + 256 * q;           // 0..1023
            int r = lin >> 4, c = lin & 15;
            As[r][c] = Arow[(size_t)r * D + k0 + c];
            Bs[r][c] = Brow[(size_t)r * D + k0 + c];
        }
        __syncthreads();
        for (int kk = 0; kk < GBK; ++kk) {
            double a[4], b[4];
            for (int u = 0; u < 4; ++u) a[u] = (double)As[tr * 4 + u][kk];
            for (int v = 0; v < 4; ++v) b[v] = (double)Bs[tc * 4 + v][kk];
            for (int u = 0; u < 4; ++u)
                for (int v = 0; v < 4; ++v) acc[u][v] = fma(a[u], b[v], acc[u][v]);
        }
        __syncthreads();
    }
    int rbase = bi * 64 + tr * 4;
    int jbase = bj * 64 + tc * 4;
    for (int u = 0; u < 4; ++u)
        for (int v = 0; v < 4; ++v)
            simT[(size_t)(rbase + u) * N + (jbase + v)] =
                (float)(acc[u][v] * (1.0 / 1024.0));
}

// Exact per-row candidate list: ballot-compact candidates, bitonic-sort
// next_pow2(m) 64-bit keys ((~v_bits)<<32)|j ascending == (v desc, j asc).
// Output: u16 column ids (position encodes order), 128 sentinels after m.
// Walk chunks ([base,base+126)) can only touch [m, m+128) past the real
// entries before stopping at the first sentinel, so stale deeper data is
// never read. sortN/cb shrink the scan for late tiles (all valid j >= cb).
__global__ __launch_bounds__(1024) void k_sort(const float* __restrict__ simT,
                                               const uint8_t* __restrict__ alive,
                                               const uint8_t* __restrict__ mgG,
                                               int t0, int sortN, int cb,
                                               uint16_t* __restrict__ lists) {
    int r = blockIdx.x;
    int i = t0 + r;
    int t = threadIdx.x;
    __shared__ uint64_t key[4096];           // 32 KB
    __shared__ int cnt;
    uint16_t* out = lists + (size_t)r * LSTR;
    if (!alive[i] || mgG[i]) {               // row dead/consumed: walk skips it
        if (t < 128) out[t] = (uint16_t)0xFFFFu;   // chunk0 sentinels
        return;
    }
    if (t == 0) cnt = 0;
    __syncthreads();
    const float* row = simT + (size_t)r * N;
    int lane = t & 63;
    for (int jj = t; jj < sortN; jj += 1024) {
        int j = cb + jj;
        float v = row[j];
        // NaN-safe: NaN fails v>=THRF; stale simT regions are masked by j>i.
        bool ok = (j > i) && (v >= THRF) && alive[j] && (!mgG[j]);
        unsigned long long mask = __ballot(ok);
        int wbase = 0;
        if (lane == 0 && mask) wbase = atomicAdd(&cnt, (int)__popcll(mask));
        wbase = __shfl(wbase, 0);
        if (ok) {
            int pos = wbase + (int)__popcll(mask & ((1ull << lane) - 1ull));
            uint32_t vb = __float_as_uint(v);    // v>0 => bit pattern monotone
            key[pos] = ((((uint64_t)(~vb)) << 32) | (uint32_t)j);
        }
    }
    __syncthreads();
    int m = cnt;
    int sm = 1; while (sm < m) sm <<= 1;     // next pow2 (>=1)
    for (int x = m + t; x < sm; x += 1024) key[x] = ~0ull;   // pad sorts to end
    __syncthreads();
    for (int k = 2; k <= sm; k <<= 1) {
        for (int s = k >> 1; s > 0; s >>= 1) {
            for (int jj = t; jj < sm; jj += 1024) {
                int l = jj ^ s;
                if (l > jj) {
                    uint64_t a = key[jj], b = key[l];
                    bool asc = ((jj & k) == 0);
                    if ((a > b) == asc) { key[jj] = b; key[l] = a; }
                }
            }
            __syncthreads();
        }
    }
    for (int jj = t; jj < m; jj += 1024)
        out[jj] = (uint16_t)(key[jj] & 0xFFFFu);
    for (int x = m + t; x < m + 128; x += 1024) out[x] = (uint16_t)0xFFFFu;
}

// Walk: 15 helper waves preload all rows' chunk0 (512x128 u16 = 128 KiB) to
// LDS, then wave 0 resolves rows sequentially. Lane 0 carries the row's own
// (consumed|dead) check; lanes 1..63 carry 2 list entries each (126/chunk).
// One shfl+ballot resolves skip/pick/refill. mw bit x = mgG[x] | !alive[x];
// merged-mask writeback is safe for all downstream consumers (see header).
__global__ __launch_bounds__(1024) void k_walk(const uint16_t* __restrict__ lists,
                                               const uint8_t* __restrict__ aliveG,
                                               uint8_t* __restrict__ mgG,
                                               int* __restrict__ partner,
                                               int t0, int* __restrict__ mcnt, int round) {
    __shared__ uint16_t ch0[TILE][128];      // 128 KiB: chunk0 of every row
    __shared__ int pt[TILE];
    int tid = threadIdx.x;
    for (int x = tid; x < TILE * 64; x += 1024) {      // ushort2 granularity
        int rr = x >> 6, e2 = x & 63;
        ((ushort2*)&ch0[rr][0])[e2] =
            *(const ushort2*)(lists + (size_t)rr * LSTR + e2 * 2);
    }
    __syncthreads();
    if (tid >= 64) return;                   // helpers done; wave 0 never barriers again
    int lane = tid;
    unsigned long long mw = 0ull;            // bit x = unavailable (consumed|dead)
    for (int w = 0; w < 8; ++w) {
        unsigned long long gm = ((const unsigned long long*)mgG)[lane * 8 + w];
        unsigned long long ga = ((const unsigned long long*)aliveG)[lane * 8 + w];
        unsigned long long bad = gm | (ga ^ 0x0101010101010101ull);  // bytes are 0/1
        for (int k = 0; k < 8; ++k)
            mw |= ((bad >> (8 * k)) & 1ull) << (8 * w + k);
    }
    int nm = 0;
    ushort2 chA = {0, 0};
    if (lane) chA = ((const ushort2*)&ch0[0][0])[lane - 1];
    for (int r = 0; r < TILE; ++r) {
        ushort2 chN = {0, 0};                // 1-row pipeline on the LDS read
        if (r + 1 < TILE && lane) chN = ((const ushort2*)&ch0[r + 1][0])[lane - 1];
        int i = t0 + r;
        ushort2 ch = chA;
        int base = 0;
        int pj = -1;
        while (true) {
            int c0, c1; bool v0, v1;
            if (lane == 0) { c0 = i; v0 = true; c1 = 0; v1 = false; }
            else {
                v0 = (ch.x != 0xFFFFu); c0 = v0 ? (int)ch.x : 0;
                v1 = (ch.y != 0xFFFFu); c1 = v1 ? (int)ch.y : 0;
            }
            unsigned long long w0 = __shfl(mw, c0 >> 6);
            unsigned long long w1 = __shfl(mw, c1 >> 6);
            bool a0 = v0 && !((w0 >> (c0 & 63)) & 1ull);
            bool a1 = v1 && !((w1 >> (c1 & 63)) & 1ull);
            unsigned long long bal = __ballot(a0 || a1);
            if (!(bal & 1ull)) break;        // row itself consumed/dead -> -1
            unsigned long long m = bal & ~1ull;
            if (m) {
                int f = __ffsll((long long)m) - 1;
                int cpick = a0 ? c0 : c1;    // within-lane order: entry0 first
                pj = __shfl(cpick, f);
                break;
            }
            unsigned long long vb = __ballot(v1);     // chunk full <=> lanes1..63 all v1
            if ((vb | 1ull) != ~0ull) break;          // sentinel seen: no cand >= thr
            base += 126;
            if (base + 126 > LSTR) break;             // safety (pad makes this unreachable)
            if (lane)
                ch = *(const ushort2*)(lists + (size_t)r * LSTR + base + (lane - 1) * 2);
        }
        if (pj >= 0) {
            if (lane == (pj >> 6)) mw |= 1ull << (pj & 63);
            if (lane == 0) pt[r] = pj;
            ++nm;                            // wave-uniform
        } else if (lane == 0) pt[r] = -1;
        chA = chN;
    }
    for (int r2 = lane; r2 < TILE; r2 += 64) partner[t0 + r2] = pt[r2];
    for (int w = 0; w < 8; ++w) {
        unsigned long long x = 0ull;
        for (int k = 0; k < 8; ++k)
            x |= ((mw >> (8 * w + k)) & 1ull) << (8 * k);
        ((unsigned long long*)mgG)[lane * 8 + w] = x;  // merged mask: safe (see header)
    }
    if (lane == 0 && nm) atomicAdd(&mcnt[round], nm);
}

__global__ void k_apply(uint8_t* __restrict__ mgB,
                        uint8_t* __restrict__ alive, uint8_t* __restrict__ consumed) {
    int x = blockIdx.x * blockDim.x + threadIdx.x;
    if (x < N) {
        uint8_t m = mgB[x];
        consumed[x] = m;                     // may include long-dead rows: k_zero idempotent
        alive[x] = (uint8_t)(alive[x] && !m);
        mgB[x] = 0;                          // reset for next round
    }
}

__global__ __launch_bounds__(256) void k_count(const uint8_t* __restrict__ alive,
                                               int* __restrict__ acnt, int slot) {
    int x = blockIdx.x * 256 + threadIdx.x;
    int lane = threadIdx.x & 63;
    unsigned long long b = __ballot(alive[x] != 0);
    if (lane == 0) atomicAdd(&acnt[slot], (int)__popcll(b));
}

__global__ void k_fuse(float* __restrict__ E, const int* __restrict__ partner) {
    int i = blockIdx.x;
    int p = partner[i];
    if (p < 0) return;
    float* ri = E + (size_t)i * D;
    const float* rp = E + (size_t)p * D;
    for (int e = threadIdx.x; e < D; e += blockDim.x)
        ri[e] = fminf(ri[e] + rp[e], 1.0f);
}

__global__ void k_zero(float* __restrict__ E, const uint8_t* __restrict__ consumed) {
    int i = blockIdx.x;
    if (!consumed[i]) return;
    float* ri = E + (size_t)i * D;
    for (int e = threadIdx.x; e < D; e += blockDim.x) ri[e] = 0.0f;
}

__global__ void k_alive_out(const uint8_t* __restrict__ alive, float* __restrict__ outA) {
    int x = blockIdx.x * blockDim.x + threadIdx.x;
    if (x < N) outA[x] = alive[x] ? 1.0f : 0.0f;
}

// AUDIT: fires ONLY on invariant violation (after+m==before, 2m<=before).
__global__ void k_diag(const int* __restrict__ mcnt, const int* __restrict__ acnt,
                       float* __restrict__ out) {
    bool bad = false;
    for (int r = 0; r < 4; ++r) {
        int before = acnt[r], after = acnt[r + 1], m = mcnt[r];
        if (after + m != before) bad = true;
        if (2 * m > before) bad = true;
        if (m < 0 || m > 2048) bad = true;
    }
    if (bad) out[0] = (float)(8.0e6 + (double)mcnt[0] * 2048.0 + (double)mcnt[1]);
}

extern "C" void kernel_launch(void* const* d_in, const int* in_sizes, int n_in,
                              void* d_out, int out_size, void* d_ws, size_t ws_size,
                              hipStream_t stream) {
    const float* Ein = (const float*)d_in[0];
    float* E = (float*)d_out;                    // 4096*1024 fp32, updated in place
    float* outAlive = E + (size_t)N * D;         // 4096 floats (0/1)

    // arena = d_in[0] after the on-stream copy below (16 MB guaranteed)
    char* ws = (char*)d_in[0];
    float* simT = (float*)ws;        ws += (size_t)TILE * N * 4;      // 8 MB
    uint16_t* lists = (uint16_t*)ws; ws += (size_t)TILE * LSTR * 2;   // 4.125 MB
    int* partner = (int*)ws;         ws += (size_t)N * 4;             // 16 KB
    int* mcnt = (int*)ws;            ws += 8 * 4;
    int* acnt = (int*)ws;            ws += 8 * 4;
    uint8_t* mgB = (uint8_t*)ws;     ws += N;    // 8B-aligned (all prior sizes %8==0)
    uint8_t* alive = (uint8_t*)ws;   ws += N;
    uint8_t* consumed = (uint8_t*)ws;            // total ~12.4 MB << 16 MB

    hipMemcpyAsync(E, Ein, (size_t)N * D * sizeof(float), hipMemcpyDeviceToDevice, stream);
    k_init<<<(N + 255) / 256, 256, 0, stream>>>(alive, mgB, mcnt, acnt);

    for (int round = 0; round < 4; ++round) {
        for (int tile = 0; tile < N / TILE; ++tile) {
            int t0 = tile * TILE;
            int bx0 = t0 / 64;                    // skip never-read columns j < t0
            int rem = N - t0;
            int sortN = 1; while (sortN < rem) sortN <<= 1;
            int cb = N - sortN;                   // all valid j > i >= t0 >= cb
            k_gemm<<<dim3(64 - bx0, TILE / 64), 256, 0, stream>>>(E, simT, t0, bx0);
            k_sort<<<TILE, 1024, 0, stream>>>(simT, alive, mgB, t0, sortN, cb, lists);
            k_walk<<<1, 1024, 0, stream>>>(lists, alive, mgB, partner, t0, mcnt, round);
        }
        k_apply<<<(N + 255) / 256, 256, 0, stream>>>(mgB, alive, consumed);
        k_count<<<16, 256, 0, stream>>>(alive, acnt, round + 1);
        k_fuse<<<N, 256, 0, stream>>>(E, partner);
        k_zero<<<N, 256, 0, stream>>>(E, consumed);
    }
    k_alive_out<<<(N + 255) / 256, 256, 0, stream>>>(alive, outAlive);
    k_diag<<<1, 1, 0, stream>>>(mcnt, acnt, E);   // conditional sentinel only
}

// Round 3
// 6823.779 us; speedup vs baseline: 1.7103x; 1.3308x over previous
//
#include <hip/hip_runtime.h>
#include <stdint.h>

#define N 4096
#define D 1024
#define TILE 512           // rows per tile (8 tiles per round)
#define THRF 0.25f
#define GBK 16
#define LSTR 4224          // u16 entries per row list slot (4096 + 128 sentinel pad)

// ---- All scratch lives in d_in[0] (16 MB; harness restores it before every
// timed launch; we copy E to d_out first on-stream). d_ws is never used.
// Numerics invariant (R6..R13-proven): sims = fp32( fp64_fma_chain(d=0..1023)/1024 ),
// ALL comparisons in fp32, (val desc, idx asc) ordering — matches np exactly.
// R17 structure (R16 + walk latency fix): exact per-row candidate lists
// (k_sort ballot-compacts candidates {j>i, alive, !mg-at-tile-start, v>=thr},
// bitonic-sorts next_pow2(m) keys ((~v_bits)<<32)|j == (val desc, idx asc),
// emits u16 column ids; position encodes order). k_walk resolves rows
// sequentially against a 4 KiB LDS BYTE mask (1 = consumed|dead): per row,
// each lane probes its 2 list entries with independent ds_read_u8 (no 64-bit
// shfl-of-bitset chain), one ballot picks the first available in sorted order,
// lane 0 marks msk[pj]=1 (same-wave DS ops are in-order, so the next row's
// probes see it). Every 64 rows a batched self-byte ballot gives a monotone
// skip hint so dead rows cost ~1 cycle-chain/64. Exactness unchanged: lists
// are a superset of candidates available at the row's turn; first available
// in sorted order == argmax; exhausted list proves no candidate >= thr.
// Merged (consumed|dead) mask writeback is safe for all downstream consumers.

__global__ void k_init(uint8_t* alive, uint8_t* mgB, int* mcnt, int* acnt) {
    int x = blockIdx.x * blockDim.x + threadIdx.x;
    if (x < N) { alive[x] = 1; mgB[x] = 0; }
    if (x < 8) { mcnt[x] = 0; acnt[x] = (x == 0) ? N : 0; }
}

// fp64 LDS-tiled GEMM -> fp32 sim tile. Rows i in [t0,t0+512), cols j in [bx0*64, 4096).
// UNCHANGED from the verified version (numerics-critical).
__global__ __launch_bounds__(256) void k_gemm(const float* __restrict__ E,
                                              float* __restrict__ simT,
                                              int t0, int bx0) {
    int bi = blockIdx.y;            // row block within tile: 0..7
    int bj = blockIdx.x + bx0;      // column block: bx0..63
    __shared__ float As[64][GBK + 1];
    __shared__ float Bs[64][GBK + 1];
    int t = threadIdx.x;
    int tr = t >> 4, tc = t & 15;
    double acc[4][4] = {};
    const float* Arow = E + ((size_t)t0 + (size_t)bi * 64) * D;
    const float* Brow = E + (size_t)bj * 64 * D;
    for (int k0 = 0; k0 < D; k0 += GBK) {
        for (int q = 0; q < 4; ++q) {
            int lin = t + 256 * q;           // 0..1023
            int r = lin >> 4, c = lin & 15;
            As[r][c] = Arow[(size_t)r * D + k0 + c];
            Bs[r][c] = Brow[(size_t)r * D + k0 + c];
        }
        __syncthreads();
        for (int kk = 0; kk < GBK; ++kk) {
            double a[4], b[4];
            for (int u = 0; u < 4; ++u) a[u] = (double)As[tr * 4 + u][kk];
            for (int v = 0; v < 4; ++v) b[v] = (double)Bs[tc * 4 + v][kk];
            for (int u = 0; u < 4; ++u)
                for (int v = 0; v < 4; ++v) acc[u][v] = fma(a[u], b[v], acc[u][v]);
        }
        __syncthreads();
    }
    int rbase = bi * 64 + tr * 4;
    int jbase = bj * 64 + tc * 4;
    for (int u = 0; u < 4; ++u)
        for (int v = 0; v < 4; ++v)
            simT[(size_t)(rbase + u) * N + (jbase + v)] =
                (float)(acc[u][v] * (1.0 / 1024.0));
}

// Exact per-row candidate list: ballot-compact candidates, bitonic-sort
// next_pow2(m) 64-bit keys ((~v_bits)<<32)|j ascending == (v desc, j asc).
// Compaction is order-agnostic: keys are unique (j embedded), so sorting the
// compacted set gives the identical list to sorting the full array.
// Output: u16 column ids, 128 sentinels after m (walk chunks can only touch
// [m, m+128) past the real entries before hitting a sentinel).
__global__ __launch_bounds__(1024) void k_sort(const float* __restrict__ simT,
                                               const uint8_t* __restrict__ alive,
                                               const uint8_t* __restrict__ mgG,
                                               int t0, int sortN, int cb,
                                               uint16_t* __restrict__ lists) {
    int r = blockIdx.x;
    int i = t0 + r;
    int t = threadIdx.x;
    __shared__ uint64_t key[4096];           // 32 KB
    __shared__ int cnt;
    uint16_t* out = lists + (size_t)r * LSTR;
    if (!alive[i] || mgG[i]) {               // row dead/consumed: walk skips it
        if (t < 128) out[t] = (uint16_t)0xFFFFu;   // chunk0 sentinels
        return;
    }
    if (t == 0) cnt = 0;
    __syncthreads();
    const float* row = simT + (size_t)r * N;
    int lane = t & 63;
    for (int jj = t; jj < sortN; jj += 1024) {
        int j = cb + jj;
        float v = row[j];
        // NaN-safe: NaN fails v>=THRF; stale simT regions are masked by j>i.
        bool ok = (j > i) && (v >= THRF) && alive[j] && (!mgG[j]);
        unsigned long long mask = __ballot(ok);
        int wbase = 0;
        if (lane == 0 && mask) wbase = atomicAdd(&cnt, (int)__popcll(mask));
        wbase = __shfl(wbase, 0);
        if (ok) {
            int pos = wbase + (int)__popcll(mask & ((1ull << lane) - 1ull));
            uint32_t vb = __float_as_uint(v);    // v>0 => bit pattern monotone
            key[pos] = ((((uint64_t)(~vb)) << 32) | (uint32_t)j);
        }
    }
    __syncthreads();
    int m = cnt;
    int sm = 1; while (sm < m) sm <<= 1;     // next pow2 (>=1)
    for (int x = m + t; x < sm; x += 1024) key[x] = ~0ull;   // pad sorts to end
    __syncthreads();
    for (int k = 2; k <= sm; k <<= 1) {
        for (int s = k >> 1; s > 0; s >>= 1) {
            for (int jj = t; jj < sm; jj += 1024) {
                int l = jj ^ s;
                if (l > jj) {
                    uint64_t a = key[jj], b = key[l];
                    bool asc = ((jj & k) == 0);
                    if ((a > b) == asc) { key[jj] = b; key[l] = a; }
                }
            }
            __syncthreads();
        }
    }
    for (int jj = t; jj < m; jj += 1024)
        out[jj] = (uint16_t)(key[jj] & 0xFFFFu);
    for (int x = m + t; x < m + 128; x += 1024) out[x] = (uint16_t)0xFFFFu;
}

// Walk: 15 helper waves preload all rows' chunk0 (128 KiB) + the 4 KiB byte
// mask to LDS, then wave 0 resolves rows sequentially (see header comment).
__global__ __launch_bounds__(1024) void k_walk(const uint16_t* __restrict__ lists,
                                               const uint8_t* __restrict__ aliveG,
                                               uint8_t* __restrict__ mgG,
                                               int* __restrict__ partner,
                                               int t0, int* __restrict__ mcnt, int round) {
    __shared__ uint16_t ch0[TILE][128];      // 128 KiB: chunk0 of every row
    __shared__ uint8_t msk[N];               // 4 KiB: 1 = unavailable (consumed|dead)
    __shared__ int pt[TILE];
    int tid = threadIdx.x;
    for (int x = tid; x < TILE * 64; x += 1024) {      // ushort2 granularity
        int rr = x >> 6, e2 = x & 63;
        ((ushort2*)&ch0[rr][0])[e2] =
            *(const ushort2*)(lists + (size_t)rr * LSTR + e2 * 2);
    }
    for (int x = tid; x < N / 8; x += 1024) {          // msk = mg | !alive (bytes 0/1)
        unsigned long long gm = ((const unsigned long long*)mgG)[x];
        unsigned long long ga = ((const unsigned long long*)aliveG)[x];
        ((unsigned long long*)msk)[x] = gm | (ga ^ 0x0101010101010101ull);
    }
    __syncthreads();
    if (tid >= 64) return;                   // helpers done; wave 0 never barriers again
    int lane = tid;
    int nm = 0;
    unsigned long long skiphint = 0ull;      // batch-start dead rows (monotone-sound)
    ushort2 chA = {0, 0};
    if (lane) chA = ((const ushort2*)&ch0[0][0])[lane - 1];
    for (int r = 0; r < TILE; ++r) {
        if ((r & 63) == 0) {                 // refresh hint once per 64 rows
            uint8_t sb = msk[t0 + r + lane];
            skiphint = __ballot(sb != 0);
        }
        ushort2 chN = {0, 0};                // 1-row pipeline on the LDS chunk read
        if (r + 1 < TILE && lane) chN = ((const ushort2*)&ch0[r + 1][0])[lane - 1];
        int i = t0 + r;
        if ((skiphint >> (r & 63)) & 1ull) { // dead at batch start -> still dead
            if (lane == 0) pt[r] = -1;
            chA = chN;
            continue;
        }
        ushort2 ch = chA;
        int base = 0;
        int pj = -1;
        while (true) {
            int c0, c1; bool v0, v1;
            if (lane == 0) { c0 = i; v0 = true; c1 = i; v1 = false; }
            else {
                v0 = (ch.x != 0xFFFFu); c0 = v0 ? (int)ch.x : 0;
                v1 = (ch.y != 0xFFFFu); c1 = v1 ? (int)ch.y : 0;
            }
            uint8_t m0 = msk[c0];            // independent ds_read_u8 probes
            uint8_t m1 = msk[c1];
            bool a0 = v0 && !m0;
            bool a1 = v1 && !m1;
            unsigned long long bal = __ballot(a0 || a1);
            if (!(bal & 1ull)) break;        // row itself consumed mid-batch -> -1
            unsigned long long m = bal & ~1ull;
            if (m) {
                int f = __ffsll((long long)m) - 1;
                int cpick = a0 ? c0 : c1;    // within-lane order: entry0 first
                pj = __shfl(cpick, f);
                break;
            }
            unsigned long long vb = __ballot(v1);     // chunk full <=> lanes1..63 all v1
            if ((vb | 1ull) != ~0ull) break;          // sentinel seen: no cand >= thr
            base += 126;
            if (base + 126 > LSTR) break;             // safety (pad makes this unreachable)
            if (lane)
                ch = *(const ushort2*)(lists + (size_t)r * LSTR + base + (lane - 1) * 2);
        }
        if (pj >= 0) {
            if (lane == 0) { pt[r] = pj; msk[pj] = 1; }   // in-order DS: next row sees it
            ++nm;                            // wave-uniform
        } else if (lane == 0) pt[r] = -1;
        chA = chN;
    }
    for (int r2 = lane; r2 < TILE; r2 += 64) partner[t0 + r2] = pt[r2];
    for (int w = lane; w < N / 8; w += 64)   // merged mask writeback: safe (see header)
        ((unsigned long long*)mgG)[w] = ((const unsigned long long*)msk)[w];
    if (lane == 0 && nm) atomicAdd(&mcnt[round], nm);
}

// apply + count fused (count ballots the locally-computed new alive value).
__global__ __launch_bounds__(256) void k_apply(uint8_t* __restrict__ mgB,
                                               uint8_t* __restrict__ alive,
                                               uint8_t* __restrict__ consumed,
                                               int* __restrict__ acnt, int slot) {
    int x = blockIdx.x * 256 + threadIdx.x;
    int lane = threadIdx.x & 63;
    uint8_t m = mgB[x];
    consumed[x] = m;                     // may include long-dead rows: k_zero idempotent
    uint8_t na = (uint8_t)(alive[x] && !m);
    alive[x] = na;
    mgB[x] = 0;                          // reset for next round
    unsigned long long b = __ballot(na != 0);
    if (lane == 0) atomicAdd(&acnt[slot], (int)__popcll(b));
}

__global__ void k_fuse(float* __restrict__ E, const int* __restrict__ partner) {
    int i = blockIdx.x;
    int p = partner[i];
    if (p < 0) return;
    float* ri = E + (size_t)i * D;
    const float* rp = E + (size_t)p * D;
    for (int e = threadIdx.x; e < D; e += blockDim.x)
        ri[e] = fminf(ri[e] + rp[e], 1.0f);
}

__global__ void k_zero(float* __restrict__ E, const uint8_t* __restrict__ consumed) {
    int i = blockIdx.x;
    if (!consumed[i]) return;
    float* ri = E + (size_t)i * D;
    for (int e = threadIdx.x; e < D; e += blockDim.x) ri[e] = 0.0f;
}

__global__ void k_alive_out(const uint8_t* __restrict__ alive, float* __restrict__ outA) {
    int x = blockIdx.x * blockDim.x + threadIdx.x;
    if (x < N) outA[x] = alive[x] ? 1.0f : 0.0f;
}

// AUDIT: fires ONLY on invariant violation (after+m==before, 2m<=before).
__global__ void k_diag(const int* __restrict__ mcnt, const int* __restrict__ acnt,
                       float* __restrict__ out) {
    bool bad = false;
    for (int r = 0; r < 4; ++r) {
        int before = acnt[r], after = acnt[r + 1], m = mcnt[r];
        if (after + m != before) bad = true;
        if (2 * m > before) bad = true;
        if (m < 0 || m > 2048) bad = true;
    }
    if (bad) out[0] = (float)(8.0e6 + (double)mcnt[0] * 2048.0 + (double)mcnt[1]);
}

extern "C" void kernel_launch(void* const* d_in, const int* in_sizes, int n_in,
                              void* d_out, int out_size, void* d_ws, size_t ws_size,
                              hipStream_t stream) {
    const float* Ein = (const float*)d_in[0];
    float* E = (float*)d_out;                    // 4096*1024 fp32, updated in place
    float* outAlive = E + (size_t)N * D;         // 4096 floats (0/1)

    // arena = d_in[0] after the on-stream copy below (16 MB guaranteed)
    char* ws = (char*)d_in[0];
    float* simT = (float*)ws;        ws += (size_t)TILE * N * 4;      // 8 MB
    uint16_t* lists = (uint16_t*)ws; ws += (size_t)TILE * LSTR * 2;   // 4.125 MB
    int* partner = (int*)ws;         ws += (size_t)N * 4;             // 16 KB
    int* mcnt = (int*)ws;            ws += 8 * 4;
    int* acnt = (int*)ws;            ws += 8 * 4;
    uint8_t* mgB = (uint8_t*)ws;     ws += N;    // 8B-aligned (all prior sizes %8==0)
    uint8_t* alive = (uint8_t*)ws;   ws += N;
    uint8_t* consumed = (uint8_t*)ws;            // total ~12.4 MB << 16 MB

    hipMemcpyAsync(E, Ein, (size_t)N * D * sizeof(float), hipMemcpyDeviceToDevice, stream);
    k_init<<<(N + 255) / 256, 256, 0, stream>>>(alive, mgB, mcnt, acnt);

    for (int round = 0; round < 4; ++round) {
        for (int tile = 0; tile < N / TILE; ++tile) {
            int t0 = tile * TILE;
            int bx0 = t0 / 64;                    // skip never-read columns j < t0
            int rem = N - t0;
            int sortN = 1; while (sortN < rem) sortN <<= 1;
            int cb = N - sortN;                   // all valid j > i >= t0 >= cb
            k_gemm<<<dim3(64 - bx0, TILE / 64), 256, 0, stream>>>(E, simT, t0, bx0);
            k_sort<<<TILE, 1024, 0, stream>>>(simT, alive, mgB, t0, sortN, cb, lists);
            k_walk<<<1, 1024, 0, stream>>>(lists, alive, mgB, partner, t0, mcnt, round);
        }
        k_apply<<<16, 256, 0, stream>>>(mgB, alive, consumed, acnt, round + 1);
        k_fuse<<<N, 256, 0, stream>>>(E, partner);
        k_zero<<<N, 256, 0, stream>>>(E, consumed);
    }
    k_alive_out<<<(N + 255) / 256, 256, 0, stream>>>(alive, outAlive);
    k_diag<<<1, 1, 0, stream>>>(mcnt, acnt, E);   // conditional sentinel only
}